// Round 5
// baseline (204.869 us; speedup 1.0000x reference)
//
#include <hip/hip_runtime.h>
#include <hip/hip_bf16.h>

#define NROWS  50000
#define MOBS   2048
#define EDIM   512
#define ODIM   256
#define NTILES 782          // ceil(NROWS/64)

typedef short s16x8 __attribute__((ext_vector_type(8)));
typedef float f32x4 __attribute__((ext_vector_type(4)));

__device__ __forceinline__ unsigned short f32_to_bf16(float f) {
    unsigned int u = __float_as_uint(f);
    u += 0x7fffu + ((u >> 16) & 1u);     // RNE (inputs finite/normal)
    return (unsigned short)(u >> 16);
}

// ---------------------------------------------------------------------------
// D1 (fused): flat 1-D grid of 1166 blocks x 256 thr.
//   b in [0,256):    G = obs^T obs, 64x64 tiles, split-K 16, atomicAdd
//   b in [256,384):  P = Wq^T Wk,  64x64 tiles, split-K 4,  atomicAdd
//   b in [384,1166): node fp32 -> bf16 in A-fragment-major order (Abf)
// Abf layout per 64-row tile: granule (kk,g) holds rows g*16+lr,
// cols kk*32 + lk*8 + j, stored at elems ((kk*4+g)*64 + lk*16+lr)*8.
// A wave's frag load in the main GEMM is then 64 lanes x 16 B contiguous.
// ---------------------------------------------------------------------------
__global__ __launch_bounds__(256) void fused_pre(const float* __restrict__ node,
                                                 const float* __restrict__ obs,
                                                 const float* __restrict__ Wq,
                                                 const float* __restrict__ Wk,
                                                 unsigned short* __restrict__ Abf,
                                                 float* __restrict__ G,
                                                 float* __restrict__ P) {
    const int b = blockIdx.x;
    if (b >= 384) {
        // ---- node -> bf16 fragment-major conversion ----
        const int tile = b - 384;
        const int t = threadIdx.x, w = t >> 6, l = t & 63;
        const int kk = l >> 2, lk = l & 3;          // lane covers cols l*8..+8
        unsigned short* tb = Abf + (size_t)tile * (64 * EDIM);
#pragma unroll
        for (int rr = 0; rr < 16; ++rr) {
            int rit = rr * 4 + w;                   // row in tile 0..63
            int gr = tile * 64 + rit;
            if (gr > NROWS - 1) gr = NROWS - 1;
            const float4* p = (const float4*)(node + (size_t)gr * EDIM + l * 8);
            float4 f0 = p[0], f1 = p[1];
            s16x8 av;
            av[0] = (short)f32_to_bf16(f0.x); av[1] = (short)f32_to_bf16(f0.y);
            av[2] = (short)f32_to_bf16(f0.z); av[3] = (short)f32_to_bf16(f0.w);
            av[4] = (short)f32_to_bf16(f1.x); av[5] = (short)f32_to_bf16(f1.y);
            av[6] = (short)f32_to_bf16(f1.z); av[7] = (short)f32_to_bf16(f1.w);
            int g = rit >> 4, lr = rit & 15;
            *(s16x8*)(tb + ((size_t)((kk * 4 + g) * 64 + lk * 16 + lr)) * 8) = av;
        }
        return;
    }
    // ---- small split-K GEMM (X^T Y pattern), atomicAdd into C ----
    __shared__ float SA[16][68];
    __shared__ float SB[16][68];
    const float *A, *B;
    float* C;
    int lda, ldb, k_lo, k_hi, bx, by;
    if (b < 256) {
        bx = b & 3; by = (b >> 2) & 3; int bz = b >> 4;
        A = obs; B = obs; C = G; lda = ODIM; ldb = ODIM;
        k_lo = bz * (MOBS / 16); k_hi = k_lo + MOBS / 16;
    } else {
        int i = b - 256;
        bx = i & 3; by = (i >> 2) & 7; int bz = i >> 5;
        A = Wq; B = Wk; C = P; lda = EDIM; ldb = ODIM;
        k_lo = bz * (EDIM / 4); k_hi = k_lo + EDIM / 4;
    }
    const int t  = threadIdx.x;
    const int tx = t & 15, ty = t >> 4;
    const int i0 = by * 64, j0 = bx * 64;

    float acc[4][4];
#pragma unroll
    for (int a = 0; a < 4; ++a)
#pragma unroll
        for (int c2 = 0; c2 < 4; ++c2) acc[a][c2] = 0.f;

    for (int k0 = k_lo; k0 < k_hi; k0 += 16) {
#pragma unroll
        for (int r = 0; r < 4; ++r) {
            int idx = t + 256 * r;
            int mm = idx & 63, kk2 = idx >> 6;
            SA[kk2][mm] = A[(size_t)(k0 + kk2) * lda + i0 + mm];
        }
#pragma unroll
        for (int r = 0; r < 4; ++r) {
            int idx = t + 256 * r;
            int jj = idx & 63, kk2 = idx >> 6;
            SB[kk2][jj] = B[(size_t)(k0 + kk2) * ldb + j0 + jj];
        }
        __syncthreads();
#pragma unroll
        for (int kk2 = 0; kk2 < 16; ++kk2) {
            float4 a4 = *(const float4*)&SA[kk2][ty * 4];
            float4 b4 = *(const float4*)&SB[kk2][tx * 4];
            float av[4] = {a4.x, a4.y, a4.z, a4.w};
            float bv[4] = {b4.x, b4.y, b4.z, b4.w};
#pragma unroll
            for (int a = 0; a < 4; ++a)
#pragma unroll
                for (int c2 = 0; c2 < 4; ++c2) acc[a][c2] += av[a] * bv[c2];
        }
        __syncthreads();
    }
#pragma unroll
    for (int a = 0; a < 4; ++a)
#pragma unroll
        for (int c2 = 0; c2 < 4; ++c2)
            atomicAdd(&C[(size_t)(i0 + ty * 4 + a) * ODIM + j0 + tx * 4 + c2],
                      acc[a][c2]);
}

// ---------------------------------------------------------------------------
// Small-chain GEMM (as R4): 64x64 tile, 4x4 micro-tile, split-K / frag out.
// ---------------------------------------------------------------------------
template <int TA, int TB, int SPLIT, int FRAG>
__global__ __launch_bounds__(256) void sgemm4(const float* __restrict__ A,
                                              const float* __restrict__ B,
                                              void* __restrict__ Cv,
                                              int NN, int KK, int lda, int ldb) {
    __shared__ float SA[16][68];
    __shared__ float SB[16][68];
    const int t  = threadIdx.x;
    const int tx = t & 15, ty = t >> 4;
    const int i0 = blockIdx.y * 64, j0 = blockIdx.x * 64;
    int k_lo = 0, k_hi = KK;
    if (SPLIT > 1) { int ch = KK / SPLIT; k_lo = blockIdx.z * ch; k_hi = k_lo + ch; }

    float acc[4][4];
#pragma unroll
    for (int a = 0; a < 4; ++a)
#pragma unroll
        for (int b = 0; b < 4; ++b) acc[a][b] = 0.f;

    for (int k0 = k_lo; k0 < k_hi; k0 += 16) {
#pragma unroll
        for (int r = 0; r < 4; ++r) {
            int idx = t + 256 * r;
            int mm, kk2;
            if (TA) { mm = idx & 63; kk2 = idx >> 6; }
            else    { kk2 = idx & 15; mm = idx >> 4; }
            SA[kk2][mm] = TA ? A[(size_t)(k0 + kk2) * lda + i0 + mm]
                             : A[(size_t)(i0 + mm) * lda + k0 + kk2];
        }
#pragma unroll
        for (int r = 0; r < 4; ++r) {
            int idx = t + 256 * r;
            int jj, kk2;
            if (TB) { kk2 = idx & 15; jj = idx >> 4; }
            else    { jj = idx & 63; kk2 = idx >> 6; }
            SB[kk2][jj] = TB ? B[(size_t)(j0 + jj) * ldb + k0 + kk2]
                             : B[(size_t)(k0 + kk2) * ldb + j0 + jj];
        }
        __syncthreads();
#pragma unroll
        for (int kk2 = 0; kk2 < 16; ++kk2) {
            float4 a4 = *(const float4*)&SA[kk2][ty * 4];
            float4 b4 = *(const float4*)&SB[kk2][tx * 4];
            float av[4] = {a4.x, a4.y, a4.z, a4.w};
            float bv[4] = {b4.x, b4.y, b4.z, b4.w};
#pragma unroll
            for (int a = 0; a < 4; ++a)
#pragma unroll
                for (int b = 0; b < 4; ++b) acc[a][b] += av[a] * bv[b];
        }
        __syncthreads();
    }

    if (FRAG) {
        unsigned short* C = (unsigned short*)Cv;
#pragma unroll
        for (int a = 0; a < 4; ++a)
#pragma unroll
            for (int b = 0; b < 4; ++b) {
                int i = i0 + ty * 4 + a;       // k-dim of main GEMM
                int j = j0 + tx * 4 + b;       // col of main GEMM
                float v = acc[a][b] + (i == j ? 1.f : 0.f);
                int f = j >> 4, lr = j & 15, kk = i >> 5, lk = (i >> 3) & 3;
                C[((size_t)((f * 16 + kk) * 64 + lk * 16 + lr)) * 8 + (i & 7)] =
                    f32_to_bf16(v);
            }
    } else if (SPLIT > 1) {
        float* C = (float*)Cv;
#pragma unroll
        for (int a = 0; a < 4; ++a)
#pragma unroll
            for (int b = 0; b < 4; ++b)
                atomicAdd(&C[(size_t)(i0 + ty * 4 + a) * NN + j0 + tx * 4 + b],
                          acc[a][b]);
    } else {
        float* C = (float*)Cv;
#pragma unroll
        for (int a = 0; a < 4; ++a) {
            float4 o = make_float4(acc[a][0], acc[a][1], acc[a][2], acc[a][3]);
            *(float4*)&C[(size_t)(i0 + ty * 4 + a) * NN + j0 + tx * 4] = o;
        }
    }
}

// ---------------------------------------------------------------------------
// Main: out = LayerNorm(node @ (U+I)), A pre-converted to frag-major bf16.
// Block: 512 thr = 8 waves, tile 64 rows x 512 cols.
// Wave w: stripe s=w>>2 (rows s*32..+32), slice c=w&3 (cols c*128..+128).
// K-loop: pure global loads (A coalesced 16B/lane from HBM-once Abf;
// B from L2-resident frag-major Uf) + MFMA. No LDS, no barriers in loop.
// acc = 2x8 f32x4 = 64 VGPR; total ~120 -> 4 waves/SIMD.
// ---------------------------------------------------------------------------
__global__ __launch_bounds__(512, 4) void gemm_stream_ln(
    const unsigned short* __restrict__ Abf, const unsigned short* __restrict__ Uf,
    const float* __restrict__ gamma, const float* __restrict__ beta,
    float* __restrict__ out) {
    __shared__ float lds_s[4][64];
    __shared__ float lds_q[4][64];
    __shared__ float lds_mu[64];
    __shared__ float lds_rs[64];

    const int t  = threadIdx.x;
    const int w  = t >> 6;
    const int l  = t & 63;
    const int s  = w >> 2;        // row stripe 0..1
    const int c  = w & 3;         // col slice 0..3
    const int lr = l & 15;
    const int lk = l >> 4;
    const int tile = blockIdx.x;

    const unsigned short* abase = Abf + (size_t)tile * (64 * EDIM) + (size_t)l * 8;
    const unsigned short* bbase = Uf + (size_t)c * 65536 + (size_t)l * 8;

    f32x4 acc[2][8];
#pragma unroll
    for (int mi = 0; mi < 2; ++mi)
#pragma unroll
        for (int ni = 0; ni < 8; ++ni)
            acc[mi][ni] = (f32x4){0.f, 0.f, 0.f, 0.f};

#pragma unroll
    for (int kk = 0; kk < 16; ++kk) {
        s16x8 afr[2], bfr[8];
#pragma unroll
        for (int mi = 0; mi < 2; ++mi)
            afr[mi] = *(const s16x8*)(abase + (size_t)(kk * 4 + 2 * s + mi) * 512);
#pragma unroll
        for (int ni = 0; ni < 8; ++ni)
            bfr[ni] = *(const s16x8*)(bbase + (size_t)(ni * 16 + kk) * 512);
#pragma unroll
        for (int mi = 0; mi < 2; ++mi)
#pragma unroll
            for (int ni = 0; ni < 8; ++ni)
                acc[mi][ni] = __builtin_amdgcn_mfma_f32_16x16x32_bf16(
                    afr[mi], bfr[ni], acc[mi][ni], 0, 0, 0);
    }

    // ---- LN stats: per-thread over 8 ni-frags, shfl over 16-lane group ----
#pragma unroll
    for (int mi = 0; mi < 2; ++mi) {
#pragma unroll
        for (int j = 0; j < 4; ++j) {
            float sm = 0.f, q = 0.f;
#pragma unroll
            for (int ni = 0; ni < 8; ++ni) {
                float v = acc[mi][ni][j];
                sm += v; q += v * v;
            }
#pragma unroll
            for (int off = 1; off < 16; off <<= 1) {
                sm += __shfl_xor(sm, off);
                q  += __shfl_xor(q, off);
            }
            if (lr == 0) {
                int row = s * 32 + mi * 16 + lk * 4 + j;
                lds_s[c][row] = sm;
                lds_q[c][row] = q;
            }
        }
    }
    __syncthreads();
    if (t < 64) {
        float sm = lds_s[0][t] + lds_s[1][t] + lds_s[2][t] + lds_s[3][t];
        float q  = lds_q[0][t] + lds_q[1][t] + lds_q[2][t] + lds_q[3][t];
        float mu  = sm * (1.f / (float)EDIM);
        float var = q * (1.f / (float)EDIM) - mu * mu;
        lds_mu[t] = mu;
        lds_rs[t] = rsqrtf(var + 1e-6f);
    }
    __syncthreads();

    float gv[8], bv[8];
#pragma unroll
    for (int ni = 0; ni < 8; ++ni) {
        int col = c * 128 + ni * 16 + lr;
        gv[ni] = gamma[col];
        bv[ni] = beta[col];
    }

#pragma unroll
    for (int mi = 0; mi < 2; ++mi) {
#pragma unroll
        for (int j = 0; j < 4; ++j) {
            int row = s * 32 + mi * 16 + lk * 4 + j;
            int gr = tile * 64 + row;
            if (gr < NROWS) {
                float mu = lds_mu[row], rs = lds_rs[row];
                float* op = out + (size_t)gr * EDIM + c * 128 + lr;
#pragma unroll
                for (int ni = 0; ni < 8; ++ni)
                    op[ni * 16] = (acc[mi][ni][j] - mu) * rs * gv[ni] + bv[ni];
            }
        }
    }
}

// ---------------------------------------------------------------------------
extern "C" void kernel_launch(void* const* d_in, const int* in_sizes, int n_in,
                              void* d_out, int out_size, void* d_ws, size_t ws_size,
                              hipStream_t stream) {
    const float* node  = (const float*)d_in[0];   // [N, E]
    const float* obs   = (const float*)d_in[1];   // [M, O]
    const float* Wq    = (const float*)d_in[2];   // [E, E]
    const float* Wk    = (const float*)d_in[3];   // [E, O]
    const float* Wv    = (const float*)d_in[4];   // [E, O]
    const float* gamma = (const float*)d_in[5];   // [E]
    const float* beta  = (const float*)d_in[6];   // [E]
    float* out = (float*)d_out;

    // ws layout (needs ~53 MB):
    //   Abf: NTILES*64*512 bf16 = 51.25 MB   (node in frag-major bf16)
    //   G [256,256] f32, P [512,256] f32, PG [512,256] f32, Uf [512,512] bf16
    unsigned short* Abf = (unsigned short*)d_ws;
    float* G  = (float*)(Abf + (size_t)NTILES * 64 * EDIM);
    float* P  = G  + ODIM * ODIM;
    float* PG = P  + EDIM * ODIM;
    unsigned short* Uf = (unsigned short*)(PG + EDIM * ODIM);

    // zero split-K accumulators G, P, PG
    hipMemsetAsync((void*)G, 0,
                   (ODIM * ODIM + 2 * EDIM * ODIM) * sizeof(float), stream);

    // D1: G (split-K 16) + P (split-K 4) + node->bf16 frag-major, one dispatch
    fused_pre<<<dim3(384 + NTILES), 256, 0, stream>>>(node, obs, Wq, Wk, Abf, G, P);
    // D2: PG = P @ G           [512,256] K=256, split-K 2
    sgemm4<0, 0, 2, 0><<<dim3(4, 8, 2), 256, 0, stream>>>(P, G, PG, ODIM, ODIM, ODIM, ODIM);
    // D3: Uf = frag(PG @ Wv^T + I) [512,512] K=256, bf16 frag-major
    sgemm4<0, 1, 1, 1><<<dim3(8, 8, 1), 256, 0, stream>>>(PG, Wv, Uf, EDIM, ODIM, ODIM, ODIM);
    // D4: out = LN(node @ (U+I))
    gemm_stream_ln<<<dim3(NTILES), 512, 0, stream>>>(Abf, Uf, gamma, beta, out);
}

// Round 6
// 147.642 us; speedup vs baseline: 1.3876x; 1.3876x over previous
//
#include <hip/hip_runtime.h>
#include <hip/hip_bf16.h>

#define NROWS  50000
#define MOBS   2048
#define EDIM   512
#define ODIM   256
#define BK     64
#define STEPS  (EDIM / BK)      // 8
#define NTILES 782              // ceil(NROWS/64)

typedef short s16x8 __attribute__((ext_vector_type(8)));
typedef float f32x4 __attribute__((ext_vector_type(4)));

__device__ __forceinline__ unsigned short f32_to_bf16(float f) {
    unsigned int u = __float_as_uint(f);
    u += 0x7fffu + ((u >> 16) & 1u);     // RNE
    return (unsigned short)(u >> 16);
}

// 8x fp32 -> bf16x8 via v_cvt_pk_bf16_f32 (RNE), 4 instrs
__device__ __forceinline__ s16x8 pack_bf16x8(f32x4 a, f32x4 b) {
    unsigned int p0, p1, p2, p3;
    asm("v_cvt_pk_bf16_f32 %0, %1, %2" : "=v"(p0) : "v"(a[0]), "v"(a[1]));
    asm("v_cvt_pk_bf16_f32 %0, %1, %2" : "=v"(p1) : "v"(a[2]), "v"(a[3]));
    asm("v_cvt_pk_bf16_f32 %0, %1, %2" : "=v"(p2) : "v"(b[0]), "v"(b[1]));
    asm("v_cvt_pk_bf16_f32 %0, %1, %2" : "=v"(p3) : "v"(b[2]), "v"(b[3]));
    union { unsigned int u[4]; s16x8 v; } r;
    r.u[0] = p0; r.u[1] = p1; r.u[2] = p2; r.u[3] = p3;
    return r.v;
}

// ---------------------------------------------------------------------------
// D1: G = obs^T obs (b<256, split-K 16) and P = Wq^T Wk (b>=256, split-K 4).
// 64x64 tiles, atomicAdd into pre-zeroed C. Flat grid of 384 blocks.
// ---------------------------------------------------------------------------
__global__ __launch_bounds__(256) void gp_fused(const float* __restrict__ obs,
                                                const float* __restrict__ Wq,
                                                const float* __restrict__ Wk,
                                                float* __restrict__ G,
                                                float* __restrict__ P) {
    __shared__ float SA[16][68];
    __shared__ float SB[16][68];
    const int b = blockIdx.x;
    const float *A, *B;
    float* C;
    int lda, ldb, k_lo, k_hi, bx, by;
    if (b < 256) {
        bx = b & 3; by = (b >> 2) & 3; int bz = b >> 4;
        A = obs; B = obs; C = G; lda = ODIM; ldb = ODIM;
        k_lo = bz * (MOBS / 16); k_hi = k_lo + MOBS / 16;
    } else {
        int i = b - 256;
        bx = i & 3; by = (i >> 2) & 7; int bz = i >> 5;
        A = Wq; B = Wk; C = P; lda = EDIM; ldb = ODIM;
        k_lo = bz * (EDIM / 4); k_hi = k_lo + EDIM / 4;
    }
    const int t  = threadIdx.x;
    const int tx = t & 15, ty = t >> 4;
    const int i0 = by * 64, j0 = bx * 64;

    float acc[4][4];
#pragma unroll
    for (int a = 0; a < 4; ++a)
#pragma unroll
        for (int c2 = 0; c2 < 4; ++c2) acc[a][c2] = 0.f;

    for (int k0 = k_lo; k0 < k_hi; k0 += 16) {
#pragma unroll
        for (int r = 0; r < 4; ++r) {
            int idx = t + 256 * r;
            int mm = idx & 63, kk2 = idx >> 6;
            SA[kk2][mm] = A[(size_t)(k0 + kk2) * lda + i0 + mm];
        }
#pragma unroll
        for (int r = 0; r < 4; ++r) {
            int idx = t + 256 * r;
            int jj = idx & 63, kk2 = idx >> 6;
            SB[kk2][jj] = B[(size_t)(k0 + kk2) * ldb + j0 + jj];
        }
        __syncthreads();
#pragma unroll
        for (int kk2 = 0; kk2 < 16; ++kk2) {
            float4 a4 = *(const float4*)&SA[kk2][ty * 4];
            float4 b4 = *(const float4*)&SB[kk2][tx * 4];
            float av[4] = {a4.x, a4.y, a4.z, a4.w};
            float bv[4] = {b4.x, b4.y, b4.z, b4.w};
#pragma unroll
            for (int a = 0; a < 4; ++a)
#pragma unroll
                for (int c2 = 0; c2 < 4; ++c2) acc[a][c2] += av[a] * bv[c2];
        }
        __syncthreads();
    }
#pragma unroll
    for (int a = 0; a < 4; ++a)
#pragma unroll
        for (int c2 = 0; c2 < 4; ++c2)
            atomicAdd(&C[(size_t)(i0 + ty * 4 + a) * ODIM + j0 + tx * 4 + c2],
                      acc[a][c2]);
}

// ---------------------------------------------------------------------------
// Small-chain GEMM: 64x64 tile, 4x4 micro-tile, split-K / frag-major output.
// ---------------------------------------------------------------------------
template <int TA, int TB, int SPLIT, int FRAG>
__global__ __launch_bounds__(256) void sgemm4(const float* __restrict__ A,
                                              const float* __restrict__ B,
                                              void* __restrict__ Cv,
                                              int NN, int KK, int lda, int ldb) {
    __shared__ float SA[16][68];
    __shared__ float SB[16][68];
    const int t  = threadIdx.x;
    const int tx = t & 15, ty = t >> 4;
    const int i0 = blockIdx.y * 64, j0 = blockIdx.x * 64;
    int k_lo = 0, k_hi = KK;
    if (SPLIT > 1) { int ch = KK / SPLIT; k_lo = blockIdx.z * ch; k_hi = k_lo + ch; }

    float acc[4][4];
#pragma unroll
    for (int a = 0; a < 4; ++a)
#pragma unroll
        for (int b = 0; b < 4; ++b) acc[a][b] = 0.f;

    for (int k0 = k_lo; k0 < k_hi; k0 += 16) {
#pragma unroll
        for (int r = 0; r < 4; ++r) {
            int idx = t + 256 * r;
            int mm, kk2;
            if (TA) { mm = idx & 63; kk2 = idx >> 6; }
            else    { kk2 = idx & 15; mm = idx >> 4; }
            SA[kk2][mm] = TA ? A[(size_t)(k0 + kk2) * lda + i0 + mm]
                             : A[(size_t)(i0 + mm) * lda + k0 + kk2];
        }
#pragma unroll
        for (int r = 0; r < 4; ++r) {
            int idx = t + 256 * r;
            int jj, kk2;
            if (TB) { kk2 = idx & 15; jj = idx >> 4; }
            else    { jj = idx & 63; kk2 = idx >> 6; }
            SB[kk2][jj] = TB ? B[(size_t)(j0 + jj) * ldb + k0 + kk2]
                             : B[(size_t)(k0 + kk2) * ldb + j0 + jj];
        }
        __syncthreads();
#pragma unroll
        for (int kk2 = 0; kk2 < 16; ++kk2) {
            float4 a4 = *(const float4*)&SA[kk2][ty * 4];
            float4 b4 = *(const float4*)&SB[kk2][tx * 4];
            float av[4] = {a4.x, a4.y, a4.z, a4.w};
            float bv[4] = {b4.x, b4.y, b4.z, b4.w};
#pragma unroll
            for (int a = 0; a < 4; ++a)
#pragma unroll
                for (int b = 0; b < 4; ++b) acc[a][b] += av[a] * bv[b];
        }
        __syncthreads();
    }

    if (FRAG) {
        unsigned short* C = (unsigned short*)Cv;
#pragma unroll
        for (int a = 0; a < 4; ++a)
#pragma unroll
            for (int b = 0; b < 4; ++b) {
                int i = i0 + ty * 4 + a;       // k-dim of main GEMM
                int j = j0 + tx * 4 + b;       // col of main GEMM
                float v = acc[a][b] + (i == j ? 1.f : 0.f);
                int f = j >> 4, lr = j & 15, kk = i >> 5, lk = (i >> 3) & 3;
                C[((size_t)((f * 16 + kk) * 64 + lk * 16 + lr)) * 8 + (i & 7)] =
                    f32_to_bf16(v);
            }
    } else if (SPLIT > 1) {
        float* C = (float*)Cv;
#pragma unroll
        for (int a = 0; a < 4; ++a)
#pragma unroll
            for (int b = 0; b < 4; ++b)
                atomicAdd(&C[(size_t)(i0 + ty * 4 + a) * NN + j0 + tx * 4 + b],
                          acc[a][b]);
    } else {
        float* C = (float*)Cv;
#pragma unroll
        for (int a = 0; a < 4; ++a) {
            float4 o = make_float4(acc[a][0], acc[a][1], acc[a][2], acc[a][3]);
            *(float4*)&C[(size_t)(i0 + ty * 4 + a) * NN + j0 + tx * 4] = o;
        }
    }
}

// ---------------------------------------------------------------------------
// Main: out = LayerNorm(node @ (U+I)).
// Block 512 thr = 8 waves; tile 64 rows x 512 cols; wave (s=w>>2, c=w&3)
// owns rows [s*32,+32) x cols [c*128,+128): acc 2x8 f32x4 = 64 VGPR.
// A: node fp32 DMA'd HBM->LDS via global_load_lds (16B), K-tiled BK=64,
//    double-buffered. LDS row = 64 fp32 = 16 granules of 16B; granule g of
//    row r holds node granule g^(r&15) (source pre-swizzled), so swizzled
//    ds_read_b128 is conflict-minimal. bf16 cvt at fragment read (cvt_pk).
// B: frag-major bf16 Uf straight from L2, 1KB coalesced wave loads.
// LDS 35KB -> 4 blocks/CU -> 32 waves/CU.
// ---------------------------------------------------------------------------
__global__ __launch_bounds__(512, 4) void gemm_dma_ln(
    const float* __restrict__ node, const unsigned short* __restrict__ Uf,
    const float* __restrict__ gamma, const float* __restrict__ beta,
    float* __restrict__ out) {
    __shared__ float Abuf[2][64 * BK];    // 2 x 16 KB
    __shared__ float lds_s[4][64];
    __shared__ float lds_q[4][64];
    __shared__ float lds_mu[64];
    __shared__ float lds_rs[64];

    const int t  = threadIdx.x;
    const int w  = t >> 6, l = t & 63;
    const int s  = w >> 2, c = w & 3;
    const int lr = l & 15, lk = l >> 4;
    const int m0 = blockIdx.x * 64;

    // staging: thread t covers (row r0 = t>>4, granule g0 = t&15) and row r0+32.
    // source granule pre-swizzled: g0 ^ (r & 15); (r0+32)&15 == r0&15.
    const int r0 = t >> 4;
    const int g0 = t & 15;
    int gr0 = m0 + r0;      if (gr0 > NROWS - 1) gr0 = NROWS - 1;
    int gr1 = m0 + r0 + 32; if (gr1 > NROWS - 1) gr1 = NROWS - 1;
    const int scol = (g0 ^ (r0 & 15)) * 4;
    const float* src0 = node + (size_t)gr0 * EDIM + scol;
    const float* src1 = node + (size_t)gr1 * EDIM + scol;

    f32x4 acc[2][8];
#pragma unroll
    for (int mi = 0; mi < 2; ++mi)
#pragma unroll
        for (int ni = 0; ni < 8; ++ni)
            acc[mi][ni] = (f32x4){0.f, 0.f, 0.f, 0.f};

    // B base: wave col-slice c -> frags f = c*8+ni; frag (f,kkg) at (f*16+kkg)*512
    const unsigned short* ubase = Uf + (size_t)(c * 8) * 16 * 512 + (size_t)l * 8;

    // ---- prologue: stage step 0 into buf 0 ----
    {
        char* lb = (char*)&Abuf[0][0] + w * 1024;
        __builtin_amdgcn_global_load_lds(
            (const __attribute__((address_space(1))) unsigned int*)src0,
            (__attribute__((address_space(3))) unsigned int*)lb, 16, 0, 0);
        __builtin_amdgcn_global_load_lds(
            (const __attribute__((address_space(1))) unsigned int*)src1,
            (__attribute__((address_space(3))) unsigned int*)(lb + 8192), 16, 0, 0);
    }
    __syncthreads();

    int cur = 0;
#pragma unroll 1
    for (int step = 0; step < STEPS; ++step) {
        if (step + 1 < STEPS) {
            char* lb = (char*)&Abuf[cur ^ 1][0] + w * 1024;
            const float* p0 = src0 + (step + 1) * BK;
            const float* p1 = src1 + (step + 1) * BK;
            __builtin_amdgcn_global_load_lds(
                (const __attribute__((address_space(1))) unsigned int*)p0,
                (__attribute__((address_space(3))) unsigned int*)lb, 16, 0, 0);
            __builtin_amdgcn_global_load_lds(
                (const __attribute__((address_space(1))) unsigned int*)p1,
                (__attribute__((address_space(3))) unsigned int*)(lb + 8192), 16, 0, 0);
        }
        const char* ab = (const char*)&Abuf[cur][0];
#pragma unroll
        for (int kk = 0; kk < 2; ++kk) {
            const unsigned short* ub = ubase + (size_t)(step * 2 + kk) * 512;
            s16x8 bfr[8];
#pragma unroll
            for (int ni = 0; ni < 8; ++ni)
                bfr[ni] = *(const s16x8*)(ub + (size_t)ni * 8192);
            s16x8 afr[2];
#pragma unroll
            for (int mi = 0; mi < 2; ++mi) {
                const int row = s * 32 + mi * 16 + lr;     // row&15 == lr
                const int gl  = kk * 8 + lk * 2;
                const char* rb = ab + row * 256;
                f32x4 a0 = *(const f32x4*)(rb + ((gl    ) ^ lr) * 16);
                f32x4 a1 = *(const f32x4*)(rb + ((gl + 1) ^ lr) * 16);
                afr[mi] = pack_bf16x8(a0, a1);
            }
#pragma unroll
            for (int mi = 0; mi < 2; ++mi)
#pragma unroll
                for (int ni = 0; ni < 8; ++ni)
                    acc[mi][ni] = __builtin_amdgcn_mfma_f32_16x16x32_bf16(
                        afr[mi], bfr[ni], acc[mi][ni], 0, 0, 0);
        }
        __syncthreads();     // drains staging DMA; buffers swap safely
        cur ^= 1;
    }

    // ---- LN stats ----
#pragma unroll
    for (int mi = 0; mi < 2; ++mi) {
#pragma unroll
        for (int j = 0; j < 4; ++j) {
            float sm = 0.f, q = 0.f;
#pragma unroll
            for (int ni = 0; ni < 8; ++ni) {
                float v = acc[mi][ni][j];
                sm += v; q += v * v;
            }
#pragma unroll
            for (int off = 1; off < 16; off <<= 1) {
                sm += __shfl_xor(sm, off);
                q  += __shfl_xor(q, off);
            }
            if (lr == 0) {
                int rl = s * 32 + mi * 16 + lk * 4 + j;
                lds_s[c][rl] = sm;
                lds_q[c][rl] = q;
            }
        }
    }
    __syncthreads();
    if (t < 64) {
        float sm = lds_s[0][t] + lds_s[1][t] + lds_s[2][t] + lds_s[3][t];
        float q  = lds_q[0][t] + lds_q[1][t] + lds_q[2][t] + lds_q[3][t];
        float mu  = sm * (1.f / (float)EDIM);
        float var = q * (1.f / (float)EDIM) - mu * mu;
        lds_mu[t] = mu;
        lds_rs[t] = rsqrtf(var + 1e-6f);
    }
    __syncthreads();

    float gv[8], bv[8];
#pragma unroll
    for (int ni = 0; ni < 8; ++ni) {
        int col = c * 128 + ni * 16 + lr;
        gv[ni] = gamma[col];
        bv[ni] = beta[col];
    }

#pragma unroll
    for (int mi = 0; mi < 2; ++mi) {
#pragma unroll
        for (int j = 0; j < 4; ++j) {
            int rl = s * 32 + mi * 16 + lk * 4 + j;
            int gr = m0 + rl;
            if (gr < NROWS) {
                float mu = lds_mu[rl], rs = lds_rs[rl];
                float* op = out + (size_t)gr * EDIM + c * 128 + lr;
#pragma unroll
                for (int ni = 0; ni < 8; ++ni)
                    op[ni * 16] = (acc[mi][ni][j] - mu) * rs * gv[ni] + bv[ni];
            }
        }
    }
}

// ---------------------------------------------------------------------------
extern "C" void kernel_launch(void* const* d_in, const int* in_sizes, int n_in,
                              void* d_out, int out_size, void* d_ws, size_t ws_size,
                              hipStream_t stream) {
    const float* node  = (const float*)d_in[0];   // [N, E]
    const float* obs   = (const float*)d_in[1];   // [M, O]
    const float* Wq    = (const float*)d_in[2];   // [E, E]
    const float* Wk    = (const float*)d_in[3];   // [E, O]
    const float* Wv    = (const float*)d_in[4];   // [E, O]
    const float* gamma = (const float*)d_in[5];   // [E]
    const float* beta  = (const float*)d_in[6];   // [E]
    float* out = (float*)d_out;

    float* ws = (float*)d_ws;
    float*          G  = ws;                        // [256,256] f32
    float*          P  = G  + ODIM * ODIM;          // [512,256] f32 (Wq^T Wk)
    float*          PG = P  + EDIM * ODIM;          // [512,256] f32
    unsigned short* Uf = (unsigned short*)(PG + EDIM * ODIM); // frag-major bf16

    // zero split-K accumulators G, P, PG
    hipMemsetAsync((void*)G, 0,
                   (ODIM * ODIM + 2 * EDIM * ODIM) * sizeof(float), stream);

    // D1: G = obs^T obs (split-K 16) + P = Wq^T Wk (split-K 4), one dispatch
    gp_fused<<<dim3(384), 256, 0, stream>>>(obs, Wq, Wk, G, P);
    // D2: PG = P @ G              [512,256] K=256, split-K 2
    sgemm4<0, 0, 2, 0><<<dim3(4, 8, 2), 256, 0, stream>>>(P, G, PG, ODIM, ODIM, ODIM, ODIM);
    // D3: Uf = frag(PG @ Wv^T + I) [512,512] K=256, bf16 frag-major
    sgemm4<0, 1, 1, 1><<<dim3(8, 8, 1), 256, 0, stream>>>(PG, Wv, Uf, EDIM, ODIM, ODIM, ODIM);
    // D4: out = LN(node @ (U+I)), DMA-staged A
    gemm_dma_ln<<<dim3(NTILES), 512, 0, stream>>>(node, Uf, gamma, beta, out);
}